// Round 4
// baseline (3233.684 us; speedup 1.0000x reference)
//
#include <hip/hip_runtime.h>
#include <math.h>

#define F 24
#define D 16
#define BATCH 2048
#define NPAIR 276
#define NTRIP 2024
#define VOCAB 10000
#define RPB 8        // rows per block
#define EPADD 28     // d-stride (floats) inside a row slab: e[f] contiguous, b128-aligned
#define ESTRIDE 452  // row-slab stride (floats): 16B-aligned, breaks mod-32 bank aliasing

// ---- compile-time index algebra for lexicographic combinations ----
__host__ __device__ constexpr int pair_base(int i) { return i * 23 - i * (i - 1) / 2; }
__host__ __device__ constexpr int pair_idx(int i, int j) { return pair_base(i) + (j - i - 1); }
__host__ __device__ constexpr int trip_base(int i) {
    return NTRIP - (24 - i) * (23 - i) * (22 - i) / 6;
}
__host__ __device__ constexpr int trip_idx(int i, int j, int k) {
    return trip_base(i) + (j - i - 1) * (46 - i - j) / 2 + (k - j - 1);
}
__host__ __device__ constexpr int pi_of(int p) {
    int i = 0;
    while (pair_base(i + 1) <= p) ++i;
    return i;
}
__host__ __device__ constexpr int pj_of(int p) { int i = pi_of(p); return i + 1 + (p - pair_base(i)); }
// coefficient-block layout: per pair p -> [g2, g3 run (23-j terms)] padded to float4
__host__ __device__ constexpr int clen(int p) { return 24 - pj_of(p); }
__host__ __device__ constexpr int cpad(int p) { return (clen(p) + 3) & ~3; }
__host__ __device__ constexpr int coff(int p) {
    int o = 0;
    for (int q = 0; q < p; ++q) o += cpad(q);
    return o;
}

// 16 contiguous pair-index chunks, balanced by trip count (~126 each)
constexpr int CHUNK_B[17] = {0, 7, 23, 30, 46, 54, 70, 86, 95, 111, 127, 143, 160, 179, 201, 227, 276};

// ---- prep: repack g2/g3 into consumption-order float4-aligned blocks in ws ----
__global__ void repack_kernel(const float* __restrict__ g2, const float* __restrict__ g3,
                              float* __restrict__ cw) {
    int p = blockIdx.x * blockDim.x + threadIdx.x;
    if (p >= NPAIR) return;
    int i = 0;
    while (pair_base(i + 1) <= p) ++i;
    int j = i + 1 + (p - pair_base(i));
    int o = 0;
    for (int q = 0; q < p; ++q) o += cpad(q);
    cw[o] = g2[p];
    int len = 23 - j;                       // g3 terms, contiguous trip ids
    int tb = (len > 0) ? trip_idx(i, j, j + 1) : 0;
    for (int k = 0; k < len; ++k) cw[o + 1 + k] = g3[tb + k];
    for (int t = 1 + len; t < cpad(p); ++t) cw[o + t] = 0.f;   // pad (never used)
}

// ---- per-chunk compute for TWO rows sharing one coefficient stream ----
template <int C>
__device__ __forceinline__ void chunk2(const float (&eA)[F], const float (&eB)[F],
                                       const float4* __restrict__ cw4,
                                       float& outA, float& outB) {
    constexpr int P0 = CHUNK_B[C], P1 = CHUNK_B[C + 1];
    float accA = 0.f, accB = 0.f;
#pragma unroll
    for (int i = 0; i < 23; ++i) {
#pragma unroll
        for (int j = i + 1; j < F; ++j) {
            if (pair_idx(i, j) >= P0 && pair_idx(i, j) < P1) {      // folds at compile time
                const int O4 = coff(pair_idx(i, j)) >> 2;           // constexpr-folded
                const int NV = (F - j + 3) >> 2;
                float c[24];
#pragma unroll
                for (int n = 0; n < NV; ++n) {                      // <=6 float4 loads / pair
                    float4 v = cw4[O4 + n];
                    c[4 * n] = v.x; c[4 * n + 1] = v.y; c[4 * n + 2] = v.z; c[4 * n + 3] = v.w;
                }
                float pA = eA[i] * eA[j], pB = eB[i] * eB[j];
                accA = fmaf(c[0], pA, accA);                        // 2nd-order
                accB = fmaf(c[0], pB, accB);
                float sA = 0.f, sB = 0.f;
#pragma unroll
                for (int k = j + 1; k < F; ++k) {                   // 3rd-order suffix
                    sA = fmaf(c[k - j], eA[k], sA);
                    sB = fmaf(c[k - j], eB[k], sB);
                }
                accA = fmaf(pA, sA, accA);
                accB = fmaf(pB, sB, accB);
            }
        }
    }
    outA = accA; outB = accB;
}

// Block = 1024 thr = 16 waves, 8 rows. Wave w = chunk w for rows rg and rg+4
// (lane = 16 d x 4 rg). Coefficients stream once per wave, used for 2 rows.
__global__ __launch_bounds__(1024) void ctr_main(
    const int* __restrict__ x, const float* __restrict__ emb,
    const float* __restrict__ lw, const float* __restrict__ lb,
    const float* __restrict__ cw, float* __restrict__ out) {
    __shared__ float s_emb[RPB][ESTRIDE];
    __shared__ int   s_idx[RPB * F];
    __shared__ float s_lw[RPB * F];
    __shared__ float s_part[RPB][16];

    const int tid = threadIdx.x;
    const int row0 = blockIdx.x * RPB;

    if (tid < RPB * F) {                        // 192 index + linear-weight gathers
        int r = tid / F, f = tid - r * F;
        int idx = x[(row0 + r) * F + f] + f * VOCAB;
        s_idx[tid] = idx;
        s_lw[tid] = lw[idx];
    }
    __syncthreads();

    if (tid < RPB * F * 4) {                    // 768 float4 gathers: emb -> LDS [r][d*28+f]
        int seg = tid >> 2, q = tid & 3;
        int r = seg / F, f = seg - r * F;
        float4 v = reinterpret_cast<const float4*>(emb)[s_idx[seg] * 4 + q];
        float* base = &s_emb[r][0];
        base[(q * 4 + 0) * EPADD + f] = v.x;
        base[(q * 4 + 1) * EPADD + f] = v.y;
        base[(q * 4 + 2) * EPADD + f] = v.z;
        base[(q * 4 + 3) * EPADD + f] = v.w;
    }
    __syncthreads();

    const int d = tid & 15, rg = (tid >> 4) & 3, w = tid >> 6;

    float eA[F], eB[F];                         // 6x ds_read_b128 each (f contiguous)
    const float4* pA = reinterpret_cast<const float4*>(&s_emb[rg][d * EPADD]);
    const float4* pB = reinterpret_cast<const float4*>(&s_emb[rg + 4][d * EPADD]);
#pragma unroll
    for (int n = 0; n < 6; ++n) {
        float4 a = pA[n], b = pB[n];
        eA[4 * n] = a.x; eA[4 * n + 1] = a.y; eA[4 * n + 2] = a.z; eA[4 * n + 3] = a.w;
        eB[4 * n] = b.x; eB[4 * n + 1] = b.y; eB[4 * n + 2] = b.z; eB[4 * n + 3] = b.w;
    }

    const float4* cw4 = reinterpret_cast<const float4*>(cw);
    float a, b;
    switch (w) {
        case 0:  chunk2<0>(eA, eB, cw4, a, b); break;
        case 1:  chunk2<1>(eA, eB, cw4, a, b); break;
        case 2:  chunk2<2>(eA, eB, cw4, a, b); break;
        case 3:  chunk2<3>(eA, eB, cw4, a, b); break;
        case 4:  chunk2<4>(eA, eB, cw4, a, b); break;
        case 5:  chunk2<5>(eA, eB, cw4, a, b); break;
        case 6:  chunk2<6>(eA, eB, cw4, a, b); break;
        case 7:  chunk2<7>(eA, eB, cw4, a, b); break;
        case 8:  chunk2<8>(eA, eB, cw4, a, b); break;
        case 9:  chunk2<9>(eA, eB, cw4, a, b); break;
        case 10: chunk2<10>(eA, eB, cw4, a, b); break;
        case 11: chunk2<11>(eA, eB, cw4, a, b); break;
        case 12: chunk2<12>(eA, eB, cw4, a, b); break;
        case 13: chunk2<13>(eA, eB, cw4, a, b); break;
        case 14: chunk2<14>(eA, eB, cw4, a, b); break;
        default: chunk2<15>(eA, eB, cw4, a, b); break;
    }

#pragma unroll
    for (int m = 1; m < 16; m <<= 1) {          // reduce over 16 d-lanes
        a += __shfl_xor(a, m, 64);
        b += __shfl_xor(b, m, 64);
    }
    if (d == 0) { s_part[rg][w] = a; s_part[rg + 4][w] = b; }
    __syncthreads();

    if (tid < 128) {                            // 8 rows x 16 chunk-partials
        int rr = tid >> 4, c = tid & 15;
        float v = s_part[rr][c];
#pragma unroll
        for (int m = 1; m < 16; m <<= 1) v += __shfl_xor(v, m, 64);
        if (c == 0) {
            float lin = lb[0];
#pragma unroll
            for (int f = 0; f < F; ++f) lin += s_lw[rr * F + f];
            float z = v + lin;
            out[row0 + rr] = 1.f / (1.f + __expf(-z));
        }
    }
}

extern "C" void kernel_launch(void* const* d_in, const int* in_sizes, int n_in,
                              void* d_out, int out_size, void* d_ws, size_t ws_size,
                              hipStream_t stream) {
    const int*   x   = (const int*)d_in[0];
    const float* emb = (const float*)d_in[1];
    const float* lw  = (const float*)d_in[2];
    const float* lb  = (const float*)d_in[3];
    const float* g2  = (const float*)d_in[4];
    const float* g3  = (const float*)d_in[5];
    float* out = (float*)d_out;
    float* cw  = (float*)d_ws;      // repacked coefficients (~16 KB)

    hipLaunchKernelGGL(repack_kernel, dim3(2), dim3(256), 0, stream, g2, g3, cw);
    hipLaunchKernelGGL(ctr_main, dim3(BATCH / RPB), dim3(1024), 0, stream,
                       x, emb, lw, lb, cw, out);
}

// Round 5
// 19.805 us; speedup vs baseline: 163.2769x; 163.2769x over previous
//
#include <hip/hip_runtime.h>
#include <math.h>

#define F 24
#define D 16
#define BATCH 2048
#define NPAIR 276
#define NTRIP 2024
#define VOCAB 10000
#define NSLOT 18            // pair-slots per wave (zero-padded to uniform count)
#define SLOTF 28            // floats per slot: [i, j, g2, pad, c0..c23]
#define SLABF (F * D + 8)   // 392: LDS row-slab stride -> max 2-way bank alias (free)

// ---- compile-time index algebra for lexicographic combinations ----
__host__ __device__ constexpr int pair_base(int i) { return i * 23 - i * (i - 1) / 2; }
__host__ __device__ constexpr int trip_base(int i) {
    return NTRIP - (24 - i) * (23 - i) * (22 - i) / 6;
}
__host__ __device__ constexpr int trip_idx(int i, int j, int k) {
    return trip_base(i) + (j - i - 1) * (46 - i - j) / 2 + (k - j - 1);
}
// chunk c (0..15) owns pairs [PB(c), PB(c+1)) -- 17 or 18 pairs each
__host__ __device__ constexpr int PB(int c) { return (NPAIR * c) / 16; }

// ---- prep: repack g2/g3 into 288 uniform consumption-order slots ----
__global__ void repack_kernel(const float* __restrict__ g2,
                              const float* __restrict__ g3,
                              float* __restrict__ cw) {
    int s = blockIdx.x * blockDim.x + threadIdx.x;
    if (s >= 16 * NSLOT) return;
    int c = s / NSLOT, q = s - c * NSLOT;
    float* o = cw + s * SLOTF;
    for (int t = 0; t < SLOTF; ++t) o[t] = 0.f;     // dummies contribute exactly 0
    int p = PB(c) + q;
    if (p < PB(c + 1)) {
        int i = 0;
        while (pair_base(i + 1) <= p) ++i;
        int j = i + 1 + (p - pair_base(i));
        o[0] = __int_as_float(i);
        o[1] = __int_as_float(j);
        o[2] = g2[p];
        if (j < 23) {
            int tb = trip_idx(i, j, j + 1);          // contiguous trip ids
            for (int k = j + 1; k < F; ++k) o[4 + k] = g3[tb + (k - j - 1)];
        }
    }
}

// Block = 1024 thr = 16 waves x (16 d-lanes x 4 rows). Wave w runs the SAME
// 18-slot loop as every other wave (only the coefficient base differs) ->
// one small I-footprint, no divergence, no runtime-indexed register arrays.
__global__ __launch_bounds__(1024, 4) void ctr_main(
    const int* __restrict__ x, const float* __restrict__ emb,
    const float* __restrict__ lw, const float* __restrict__ lb,
    const float* __restrict__ cw, float* __restrict__ out) {
    __shared__ float s_e[4 * SLABF];
    __shared__ int   s_idx[4 * F];
    __shared__ float s_lw[4 * F];
    __shared__ float s_part[4][16];

    const int tid = threadIdx.x;
    const int row0 = blockIdx.x * 4;

    if (tid < 4 * F) {                       // 96 index + linear-weight gathers
        int r = tid / F, f = tid - r * F;
        int idx = x[(row0 + r) * F + f] + f * VOCAB;
        s_idx[tid] = idx;
        s_lw[tid] = lw[idx];
    }
    __syncthreads();

    if (tid < 4 * F * 4) {                   // 384 float4 gathers: emb -> LDS [r][f*16+d]
        int seg = tid >> 2, q = tid & 3;
        int r = seg / F, f = seg - r * F;
        float4 v = reinterpret_cast<const float4*>(emb)[s_idx[seg] * 4 + q];
        float* b = &s_e[r * SLABF + f * D + q * 4];
        b[0] = v.x; b[1] = v.y; b[2] = v.z; b[3] = v.w;   // ds_write_b128
    }
    __syncthreads();

    const int d = tid & 15;
    const int r = (tid >> 4) & 3;
    const int w = __builtin_amdgcn_readfirstlane(tid >> 6);   // SGPR-uniform chunk id
    const float* se = &s_e[r * SLABF];

    float e[F];                              // register copy, statically indexed only
#pragma unroll
    for (int f = 0; f < F; ++f) e[f] = se[f * D + d];

    const float4* cp = reinterpret_cast<const float4*>(cw) + w * (NSLOT * 7);
    float acc = 0.f;
#pragma unroll 2
    for (int s = 0; s < NSLOT; ++s) {
        float4 h  = cp[s * 7 + 0];
        float4 c0 = cp[s * 7 + 1], c1 = cp[s * 7 + 2], c2 = cp[s * 7 + 3];
        float4 c3 = cp[s * 7 + 4], c4 = cp[s * 7 + 5], c5 = cp[s * 7 + 6];
        int i = __float_as_int(h.x), j = __float_as_int(h.y);
        float ei = se[i * D + d];            // runtime index -> LDS (2 reads/slot)
        float ej = se[j * D + d];
        // zero-padded 24-term dot: c[k]=g3[ijk] for k>j else 0 (FP-exact zeros)
        float ta = h.z, tb = 0.f;            // ta seeded with g2; two chains for ILP
        ta = fmaf(c0.x, e[0],  ta); tb = fmaf(c0.y, e[1],  tb);
        ta = fmaf(c0.z, e[2],  ta); tb = fmaf(c0.w, e[3],  tb);
        ta = fmaf(c1.x, e[4],  ta); tb = fmaf(c1.y, e[5],  tb);
        ta = fmaf(c1.z, e[6],  ta); tb = fmaf(c1.w, e[7],  tb);
        ta = fmaf(c2.x, e[8],  ta); tb = fmaf(c2.y, e[9],  tb);
        ta = fmaf(c2.z, e[10], ta); tb = fmaf(c2.w, e[11], tb);
        ta = fmaf(c3.x, e[12], ta); tb = fmaf(c3.y, e[13], tb);
        ta = fmaf(c3.z, e[14], ta); tb = fmaf(c3.w, e[15], tb);
        ta = fmaf(c4.x, e[16], ta); tb = fmaf(c4.y, e[17], tb);
        ta = fmaf(c4.z, e[18], ta); tb = fmaf(c4.w, e[19], tb);
        ta = fmaf(c5.x, e[20], ta); tb = fmaf(c5.y, e[21], tb);
        ta = fmaf(c5.z, e[22], ta); tb = fmaf(c5.w, e[23], tb);
        acc = fmaf(ei * ej, ta + tb, acc);   // pij * (g2 + suffix-dot)
    }

#pragma unroll
    for (int m = 1; m < 16; m <<= 1) acc += __shfl_xor(acc, m, 64);
    if (d == 0) s_part[r][w] = acc;
    __syncthreads();

    if (tid < 64) {                          // 4 rows x 16 chunk-partials
        int rr = tid >> 4, c = tid & 15;
        float v = s_part[rr][c];
#pragma unroll
        for (int m = 1; m < 16; m <<= 1) v += __shfl_xor(v, m, 64);
        if (c == 0) {
            float lin = lb[0];
#pragma unroll
            for (int f = 0; f < F; ++f) lin += s_lw[rr * F + f];
            float z = v + lin;
            out[row0 + rr] = 1.f / (1.f + __expf(-z));
        }
    }
}

extern "C" void kernel_launch(void* const* d_in, const int* in_sizes, int n_in,
                              void* d_out, int out_size, void* d_ws, size_t ws_size,
                              hipStream_t stream) {
    const int*   x   = (const int*)d_in[0];
    const float* emb = (const float*)d_in[1];
    const float* lw  = (const float*)d_in[2];
    const float* lb  = (const float*)d_in[3];
    const float* g2  = (const float*)d_in[4];
    const float* g3  = (const float*)d_in[5];
    float* out = (float*)d_out;
    float* cw  = (float*)d_ws;      // 288 slots x 28 floats = 32 KB

    hipLaunchKernelGGL(repack_kernel, dim3(2), dim3(256), 0, stream, g2, g3, cw);
    hipLaunchKernelGGL(ctr_main, dim3(BATCH / 4), dim3(1024), 0, stream,
                       x, emb, lw, lb, cw, out);
}